// Round 1
// baseline (448.582 us; speedup 1.0000x reference)
//
#include <hip/hip_runtime.h>

#define KLAB 32
#define FDIM 32
#define NPIX (512 * 512)
#define BATCH 8
#define EPSF 1e-12f

__device__ __forceinline__ int clampk(int k) { return k < 0 ? 0 : (k > KLAB - 1 ? KLAB - 1 : k); }

__device__ __forceinline__ float block_reduce(float v, float* red, int tid) {
    red[tid] = v;
    __syncthreads();
    for (int s = 128; s > 0; s >>= 1) {
        if (tid < s) red[tid] += red[tid + s];
        __syncthreads();
    }
    float r = red[0];
    __syncthreads();
    return r;
}

// Pass 1: per-(b,k) counts and per-(b,f,k) feature sums.
// LDS layout [F][K]: bank index = k -> distinct labels hit distinct banks.
__global__ __launch_bounds__(256) void k_sums(
    const float* __restrict__ x, const int* __restrict__ lab,
    float* __restrict__ g_sums, unsigned int* __restrict__ g_cnt)
{
    __shared__ float s_sums[FDIM][KLAB];
    __shared__ unsigned int s_cnt[KLAB];
    const int tid = threadIdx.x;
    const int b = blockIdx.y;
    float* sflat = &s_sums[0][0];
    for (int i = tid; i < FDIM * KLAB; i += 256) sflat[i] = 0.f;
    if (tid < KLAB) s_cnt[tid] = 0u;
    __syncthreads();

    const size_t xbase = (size_t)b * FDIM * NPIX;
    const size_t lbase = (size_t)b * NPIX;
    const int px_per_block = NPIX / gridDim.x;       // 2048 at grid.x=128
    const int n0 = blockIdx.x * px_per_block;

    for (int it = 0; it < px_per_block; it += 1024) {
        const int n = n0 + it + tid * 4;
        const int4 l4 = *reinterpret_cast<const int4*>(&lab[lbase + n]);
        const int k0 = clampk(l4.x), k1 = clampk(l4.y), k2 = clampk(l4.z), k3 = clampk(l4.w);
        atomicAdd(&s_cnt[k0], 1u);
        atomicAdd(&s_cnt[k1], 1u);
        atomicAdd(&s_cnt[k2], 1u);
        atomicAdd(&s_cnt[k3], 1u);
#pragma unroll
        for (int f = 0; f < FDIM; ++f) {
            const float4 v = *reinterpret_cast<const float4*>(&x[xbase + (size_t)f * NPIX + n]);
            atomicAdd(&s_sums[f][k0], v.x);
            atomicAdd(&s_sums[f][k1], v.y);
            atomicAdd(&s_sums[f][k2], v.z);
            atomicAdd(&s_sums[f][k3], v.w);
        }
    }
    __syncthreads();
    float* gs = g_sums + (size_t)b * FDIM * KLAB;
    for (int i = tid; i < FDIM * KLAB; i += 256) atomicAdd(&gs[i], sflat[i]);
    if (tid < KLAB) atomicAdd(&g_cnt[b * KLAB + tid], s_cnt[tid]);
}

// Pass 2: per-pixel ||mu_label - x||, hinge^2, per-(b,k) sums.
__global__ __launch_bounds__(256) void k_var(
    const float* __restrict__ x, const int* __restrict__ lab,
    const float* __restrict__ g_sums, const unsigned int* __restrict__ g_cnt,
    float* __restrict__ g_vsum)
{
    __shared__ float mu_s[FDIM][KLAB];
    __shared__ float vloc[KLAB];
    const int tid = threadIdx.x;
    const int b = blockIdx.y;
    for (int i = tid; i < FDIM * KLAB; i += 256) {
        const int k = i & (KLAB - 1);
        const float c = (float)g_cnt[b * KLAB + k];
        (&mu_s[0][0])[i] = g_sums[(size_t)b * FDIM * KLAB + i] / fmaxf(c, 1.f);
    }
    if (tid < KLAB) vloc[tid] = 0.f;
    __syncthreads();

    const size_t xbase = (size_t)b * FDIM * NPIX;
    const size_t lbase = (size_t)b * NPIX;
    const int px_per_block = NPIX / gridDim.x;
    const int n0 = blockIdx.x * px_per_block;

    for (int it = 0; it < px_per_block; it += 1024) {
        const int n = n0 + it + tid * 4;
        const int4 l4 = *reinterpret_cast<const int4*>(&lab[lbase + n]);
        const int k0 = clampk(l4.x), k1 = clampk(l4.y), k2 = clampk(l4.z), k3 = clampk(l4.w);
        float d0 = 0.f, d1 = 0.f, d2 = 0.f, d3 = 0.f;
#pragma unroll
        for (int f = 0; f < FDIM; ++f) {
            const float4 v = *reinterpret_cast<const float4*>(&x[xbase + (size_t)f * NPIX + n]);
            float t0 = v.x - mu_s[f][k0]; d0 += t0 * t0;
            float t1 = v.y - mu_s[f][k1]; d1 += t1 * t1;
            float t2 = v.z - mu_s[f][k2]; d2 += t2 * t2;
            float t3 = v.w - mu_s[f][k3]; d3 += t3 * t3;
        }
        float h;
        h = fmaxf(sqrtf(d0 + EPSF) - 0.5f, 0.f); atomicAdd(&vloc[k0], h * h);
        h = fmaxf(sqrtf(d1 + EPSF) - 0.5f, 0.f); atomicAdd(&vloc[k1], h * h);
        h = fmaxf(sqrtf(d2 + EPSF) - 0.5f, 0.f); atomicAdd(&vloc[k2], h * h);
        h = fmaxf(sqrtf(d3 + EPSF) - 0.5f, 0.f); atomicAdd(&vloc[k3], h * h);
    }
    __syncthreads();
    if (tid < KLAB) atomicAdd(&g_vsum[b * KLAB + tid], vloc[tid]);
}

// Epilogue: var combine + pairwise push term + reg term -> scalar.
__global__ __launch_bounds__(256) void k_final(
    const float* __restrict__ g_sums, const unsigned int* __restrict__ g_cnt,
    const float* __restrict__ g_vsum, float* __restrict__ out)
{
    __shared__ float mu_s[FDIM][KLAB];
    __shared__ float cnt_s[KLAB];
    __shared__ float red[256];
    const int tid = threadIdx.x;
    float total = 0.f;

    for (int b = 0; b < BATCH; ++b) {
        if (tid < KLAB) cnt_s[tid] = (float)g_cnt[b * KLAB + tid];
        __syncthreads();
        for (int i = tid; i < FDIM * KLAB; i += 256) {
            const int k = i & (KLAB - 1);
            (&mu_s[0][0])[i] = g_sums[(size_t)b * FDIM * KLAB + i] / fmaxf(cnt_s[k], 1.f);
        }
        __syncthreads();

        float pres = 0.f, varp = 0.f, regp = 0.f, distp = 0.f;
        if (tid < KLAB && cnt_s[tid] > 0.f) {
            pres = 1.f;
            varp = g_vsum[b * KLAB + tid] / fmaxf(cnt_s[tid], 1.f);
            float s = 0.f;
            for (int f = 0; f < FDIM; ++f) { float m = mu_s[f][tid]; s += m * m; }
            regp = sqrtf(s + EPSF);
        }
        for (int idx = tid; idx < KLAB * KLAB; idx += 256) {
            const int i = idx >> 5, j = idx & 31;
            if (i < j && cnt_s[i] > 0.f && cnt_s[j] > 0.f) {
                float s = 0.f;
                for (int f = 0; f < FDIM; ++f) { float d = mu_s[f][i] - mu_s[f][j]; s += d * d; }
                const float dist = sqrtf(s + EPSF);
                const float hg = fmaxf(1.5f - dist, 0.f);
                distp += hg * hg;
            }
        }

        const float C  = block_reduce(pres,  red, tid);
        const float vn = block_reduce(varp,  red, tid);
        const float rg = block_reduce(regp,  red, tid);
        const float dl = block_reduce(distp, red, tid);
        if (tid == 0) {
            const float var_b = (C > 0.f) ? vn / fmaxf(C, 1.f) : 0.f;
            const float dis_b = (C > 2.f) ? dl / fmaxf(C * (C - 1.f), 1.f) : 0.f;
            const float reg_b = (C > 1.f) ? rg : 0.f;
            total += 1.0f * var_b + 1.0f * dis_b + 0.001f * reg_b;
        }
        __syncthreads();
    }
    if (tid == 0) out[0] = total;
}

extern "C" void kernel_launch(void* const* d_in, const int* in_sizes, int n_in,
                              void* d_out, int out_size, void* d_ws, size_t ws_size,
                              hipStream_t stream) {
    const float* x = (const float*)d_in[0];
    const int* lab = (const int*)d_in[1];
    float* out = (float*)d_out;

    // workspace: sums [B][F][K] | counts [B][K] (u32) | vsums [B][K]
    float* g_sums = (float*)d_ws;
    unsigned int* g_cnt = (unsigned int*)((char*)d_ws + (size_t)BATCH * FDIM * KLAB * 4);
    float* g_vsum = (float*)((char*)d_ws + (size_t)BATCH * FDIM * KLAB * 4 + (size_t)BATCH * KLAB * 4);
    hipMemsetAsync(d_ws, 0, (size_t)(BATCH * FDIM * KLAB + 2 * BATCH * KLAB) * 4, stream);

    dim3 grid(128, BATCH);
    k_sums<<<grid, 256, 0, stream>>>(x, lab, g_sums, g_cnt);
    k_var<<<grid, 256, 0, stream>>>(x, lab, g_sums, g_cnt, g_vsum);
    k_final<<<1, 256, 0, stream>>>(g_sums, g_cnt, g_vsum, out);
}

// Round 2
// 188.929 us; speedup vs baseline: 2.3743x; 2.3743x over previous
//
#include <hip/hip_runtime.h>

#define KLAB 32
#define FDIM 32
#define NPIX (512 * 512)
#define BATCH 8
#define EPSF 1e-12f

typedef __attribute__((ext_vector_type(8))) short bf16x8;
typedef __attribute__((ext_vector_type(4))) float f32x4;

__device__ __forceinline__ short f2bf(float f) {
    unsigned u = __builtin_bit_cast(unsigned, f);
    unsigned r = (u + 0x7FFFu + ((u >> 16) & 1u)) >> 16;   // RNE
    return (short)r;
}

__device__ __forceinline__ float block_reduce(float v, float* red, int tid) {
    red[tid] = v;
    __syncthreads();
    for (int s = 128; s > 0; s >>= 1) {
        if (tid < s) red[tid] += red[tid + s];
        __syncthreads();
    }
    float r = red[0];
    __syncthreads();
    return r;
}

// Pass 1: sums[b][f][k] = sum_n x[b][f][n]*onehot(lab[n]==k) via MFMA one-hot GEMM.
// Counts via an extra all-ones A fragment (row 0 of its C = counts).
__global__ __launch_bounds__(256) void k_msums(
    const float* __restrict__ x, const int* __restrict__ lab,
    float* __restrict__ g_sums, float* __restrict__ g_cnt)
{
    const int tid = threadIdx.x;
    const int b = blockIdx.y;
    const int w = tid >> 6, l = tid & 63;
    const int row = l & 15, grp = l >> 4;
    const int gw = blockIdx.x * 4 + w;              // 0..1023 waves per batch
    const int STEPS = NPIX / 32 / 1024;             // 8
    const size_t xb = (size_t)b * FDIM * NPIX;
    const size_t lb = (size_t)b * NPIX;

    f32x4 acc00{}, acc01{}, acc10{}, acc11{}, accC0{}, accC1{};
    bf16x8 ones;
#pragma unroll
    for (int j = 0; j < 8; ++j) ones[j] = (short)0x3F80;

    const float* xr0 = x + xb + (size_t)row * NPIX;
    const float* xr1 = x + xb + (size_t)(row + 16) * NPIX;

    for (int s = 0; s < STEPS; ++s) {
        const int p0 = (gw * STEPS + s) * 32;
        const int pg = p0 + grp * 8;
        const int4 la = *reinterpret_cast<const int4*>(&lab[lb + pg]);
        const int4 lc = *reinterpret_cast<const int4*>(&lab[lb + pg + 4]);
        const f32x4 v0 = *reinterpret_cast<const f32x4*>(&xr0[pg]);
        const f32x4 v1 = *reinterpret_cast<const f32x4*>(&xr0[pg + 4]);
        const f32x4 v2 = *reinterpret_cast<const f32x4*>(&xr1[pg]);
        const f32x4 v3 = *reinterpret_cast<const f32x4*>(&xr1[pg + 4]);

        bf16x8 a0, a1, b0, b1;
        a0[0]=f2bf(v0.x); a0[1]=f2bf(v0.y); a0[2]=f2bf(v0.z); a0[3]=f2bf(v0.w);
        a0[4]=f2bf(v1.x); a0[5]=f2bf(v1.y); a0[6]=f2bf(v1.z); a0[7]=f2bf(v1.w);
        a1[0]=f2bf(v2.x); a1[1]=f2bf(v2.y); a1[2]=f2bf(v2.z); a1[3]=f2bf(v2.w);
        a1[4]=f2bf(v3.x); a1[5]=f2bf(v3.y); a1[6]=f2bf(v3.z); a1[7]=f2bf(v3.w);
        const int lj[8] = {la.x, la.y, la.z, la.w, lc.x, lc.y, lc.z, lc.w};
#pragma unroll
        for (int j = 0; j < 8; ++j) {
            b0[j] = (lj[j] == row)      ? (short)0x3F80 : (short)0;
            b1[j] = (lj[j] == row + 16) ? (short)0x3F80 : (short)0;
        }
        acc00 = __builtin_amdgcn_mfma_f32_16x16x32_bf16(a0, b0, acc00, 0, 0, 0);
        acc10 = __builtin_amdgcn_mfma_f32_16x16x32_bf16(a1, b0, acc10, 0, 0, 0);
        acc01 = __builtin_amdgcn_mfma_f32_16x16x32_bf16(a0, b1, acc01, 0, 0, 0);
        acc11 = __builtin_amdgcn_mfma_f32_16x16x32_bf16(a1, b1, acc11, 0, 0, 0);
        accC0 = __builtin_amdgcn_mfma_f32_16x16x32_bf16(ones, b0, accC0, 0, 0, 0);
        accC1 = __builtin_amdgcn_mfma_f32_16x16x32_bf16(ones, b1, accC1, 0, 0, 0);
    }

    // Block-level LDS reduce of the 4 waves' [F][K] partials, then global atomics.
    __shared__ float s_red[4][FDIM * KLAB];
#pragma unroll
    for (int i = 0; i < 4; ++i) {
        // C layout: col = lane&15, row = (lane>>4)*4 + i  [measured m89]
        const int fr = grp * 4 + i;
        s_red[w][(fr)      * KLAB + row]      = acc00[i];
        s_red[w][(fr)      * KLAB + row + 16] = acc01[i];
        s_red[w][(fr + 16) * KLAB + row]      = acc10[i];
        s_red[w][(fr + 16) * KLAB + row + 16] = acc11[i];
    }
    __syncthreads();
    float* gs = g_sums + (size_t)b * FDIM * KLAB;
    for (int i = tid; i < FDIM * KLAB; i += 256)
        atomicAdd(&gs[i], s_red[0][i] + s_red[1][i] + s_red[2][i] + s_red[3][i]);
    if (l < 16) {   // counts: row 0 of ones-GEMM = per-chunk label counts
        atomicAdd(&g_cnt[b * KLAB + l],      accC0[0]);
        atomicAdd(&g_cnt[b * KLAB + l + 16], accC1[0]);
    }
}

// Pass 2: per-pixel ||mu_label - x||, hinge^2, per-(b,k) sums. Depth-2 feature prefetch.
__global__ __launch_bounds__(256) void k_var(
    const float* __restrict__ x, const int* __restrict__ lab,
    const float* __restrict__ g_sums, const float* __restrict__ g_cnt,
    float* __restrict__ g_vsum)
{
    __shared__ float mu_s[FDIM][KLAB];
    __shared__ float vloc[KLAB];
    const int tid = threadIdx.x;
    const int b = blockIdx.y;
    for (int i = tid; i < FDIM * KLAB; i += 256) {
        const int k = i & (KLAB - 1);
        const float c = g_cnt[b * KLAB + k];
        (&mu_s[0][0])[i] = g_sums[(size_t)b * FDIM * KLAB + i] / fmaxf(c, 1.f);
    }
    if (tid < KLAB) vloc[tid] = 0.f;
    __syncthreads();

    const int n = blockIdx.x * 1024 + tid * 4;      // 4 pixels/thread, 256 blocks/batch
    const int4 l4 = *reinterpret_cast<const int4*>(&lab[(size_t)b * NPIX + n]);
    const int k0 = l4.x & 31, k1 = l4.y & 31, k2 = l4.z & 31, k3 = l4.w & 31;
    const float* xp = x + (size_t)b * FDIM * NPIX + n;

    f32x4 va = *reinterpret_cast<const f32x4*>(xp);
    f32x4 vb = *reinterpret_cast<const f32x4*>(xp + NPIX);
    float d0 = 0.f, d1 = 0.f, d2 = 0.f, d3 = 0.f;
#pragma unroll
    for (int f = 0; f < FDIM; ++f) {
        f32x4 vn{};
        if (f + 2 < FDIM) vn = *reinterpret_cast<const f32x4*>(xp + (size_t)(f + 2) * NPIX);
        const float m0 = mu_s[f][k0], m1 = mu_s[f][k1], m2 = mu_s[f][k2], m3 = mu_s[f][k3];
        float t0 = va.x - m0; d0 += t0 * t0;
        float t1 = va.y - m1; d1 += t1 * t1;
        float t2 = va.z - m2; d2 += t2 * t2;
        float t3 = va.w - m3; d3 += t3 * t3;
        va = vb; vb = vn;
    }
    float h;
    h = fmaxf(sqrtf(d0 + EPSF) - 0.5f, 0.f); atomicAdd(&vloc[k0], h * h);
    h = fmaxf(sqrtf(d1 + EPSF) - 0.5f, 0.f); atomicAdd(&vloc[k1], h * h);
    h = fmaxf(sqrtf(d2 + EPSF) - 0.5f, 0.f); atomicAdd(&vloc[k2], h * h);
    h = fmaxf(sqrtf(d3 + EPSF) - 0.5f, 0.f); atomicAdd(&vloc[k3], h * h);
    __syncthreads();
    if (tid < KLAB) atomicAdd(&g_vsum[b * KLAB + tid], vloc[tid]);
}

// Epilogue: var combine + pairwise push term + reg term -> scalar.
__global__ __launch_bounds__(256) void k_final(
    const float* __restrict__ g_sums, const float* __restrict__ g_cnt,
    const float* __restrict__ g_vsum, float* __restrict__ out)
{
    __shared__ float mu_s[FDIM][KLAB];
    __shared__ float cnt_s[KLAB];
    __shared__ float red[256];
    const int tid = threadIdx.x;
    float total = 0.f;

    for (int b = 0; b < BATCH; ++b) {
        if (tid < KLAB) cnt_s[tid] = g_cnt[b * KLAB + tid];
        __syncthreads();
        for (int i = tid; i < FDIM * KLAB; i += 256) {
            const int k = i & (KLAB - 1);
            (&mu_s[0][0])[i] = g_sums[(size_t)b * FDIM * KLAB + i] / fmaxf(cnt_s[k], 1.f);
        }
        __syncthreads();

        float pres = 0.f, varp = 0.f, regp = 0.f, distp = 0.f;
        if (tid < KLAB && cnt_s[tid] > 0.f) {
            pres = 1.f;
            varp = g_vsum[b * KLAB + tid] / fmaxf(cnt_s[tid], 1.f);
            float s = 0.f;
            for (int f = 0; f < FDIM; ++f) { float m = mu_s[f][tid]; s += m * m; }
            regp = sqrtf(s + EPSF);
        }
        for (int idx = tid; idx < KLAB * KLAB; idx += 256) {
            const int i = idx >> 5, j = idx & 31;
            if (i < j && cnt_s[i] > 0.f && cnt_s[j] > 0.f) {
                float s = 0.f;
                for (int f = 0; f < FDIM; ++f) { float d = mu_s[f][i] - mu_s[f][j]; s += d * d; }
                const float dist = sqrtf(s + EPSF);
                const float hg = fmaxf(1.5f - dist, 0.f);
                distp += hg * hg;
            }
        }

        const float C  = block_reduce(pres,  red, tid);
        const float vn = block_reduce(varp,  red, tid);
        const float rg = block_reduce(regp,  red, tid);
        const float dl = block_reduce(distp, red, tid);
        if (tid == 0) {
            const float var_b = (C > 0.f) ? vn / fmaxf(C, 1.f) : 0.f;
            const float dis_b = (C > 2.f) ? dl / fmaxf(C * (C - 1.f), 1.f) : 0.f;
            const float reg_b = (C > 1.f) ? rg : 0.f;
            total += 1.0f * var_b + 1.0f * dis_b + 0.001f * reg_b;
        }
        __syncthreads();
    }
    if (tid == 0) out[0] = total;
}

extern "C" void kernel_launch(void* const* d_in, const int* in_sizes, int n_in,
                              void* d_out, int out_size, void* d_ws, size_t ws_size,
                              hipStream_t stream) {
    const float* x = (const float*)d_in[0];
    const int* lab = (const int*)d_in[1];
    float* out = (float*)d_out;

    // workspace: sums [B][F][K] | counts [B][K] | vsums [B][K]  (all float)
    float* g_sums = (float*)d_ws;
    float* g_cnt  = g_sums + (size_t)BATCH * FDIM * KLAB;
    float* g_vsum = g_cnt + (size_t)BATCH * KLAB;
    hipMemsetAsync(d_ws, 0, (size_t)(BATCH * FDIM * KLAB + 2 * BATCH * KLAB) * 4, stream);

    dim3 grid1(256, BATCH);    // 1024 waves/batch, 8 MFMA k-steps each
    k_msums<<<grid1, 256, 0, stream>>>(x, lab, g_sums, g_cnt);
    dim3 grid2(256, BATCH);    // 1024 px/block, 4 px/thread
    k_var<<<grid2, 256, 0, stream>>>(x, lab, g_sums, g_cnt, g_vsum);
    k_final<<<1, 256, 0, stream>>>(g_sums, g_cnt, g_vsum, out);
}

// Round 5
// 174.768 us; speedup vs baseline: 2.5667x; 1.0810x over previous
//
#include <hip/hip_runtime.h>

#define KLAB 32
#define FDIM 32
#define NPIX (512 * 512)
#define BATCH 8
#define EPSF 1e-12f

typedef __attribute__((ext_vector_type(8))) short bf16x8;
typedef __attribute__((ext_vector_type(4))) float f32x4;

__device__ __forceinline__ short f2bf(float f) {
    unsigned u = __builtin_bit_cast(unsigned, f);
    unsigned r = (u + 0x7FFFu + ((u >> 16) & 1u)) >> 16;   // RNE
    return (short)r;
}

__device__ __forceinline__ float bf2f(short s) {
    return __builtin_bit_cast(float, (unsigned)((unsigned short)s) << 16);
}

// Pass 1: per-label sums via MFMA one-hot GEMM, depth-2 load pipeline,
// and stash bf16(x) to ws for pass 2 (halves pass-2 read traffic).
__global__ __launch_bounds__(256, 4) void k_msums(
    const float* __restrict__ x, const int* __restrict__ lab,
    float* __restrict__ g_sums, float* __restrict__ g_cnt,
    short* __restrict__ xbf)
{
    const int tid = threadIdx.x;
    const int b = blockIdx.y;
    const int w = tid >> 6, l = tid & 63;
    const int row = l & 15, grp = l >> 4;
    const int gw = blockIdx.x * 4 + w;              // 0..1023 waves per batch
    const int STEPS = NPIX / 32 / 1024;             // 8
    const size_t xb = (size_t)b * FDIM * NPIX;
    const size_t lb = (size_t)b * NPIX;

    f32x4 acc00{}, acc01{}, acc10{}, acc11{}, accC0{}, accC1{};
    bf16x8 ones;
#pragma unroll
    for (int j = 0; j < 8; ++j) ones[j] = (short)0x3F80;

    const float* xr0 = x + xb + (size_t)row * NPIX;
    const float* xr1 = x + xb + (size_t)(row + 16) * NPIX;
    short* sr0 = xbf + xb + (size_t)row * NPIX;
    short* sr1 = xbf + xb + (size_t)(row + 16) * NPIX;

    // prologue: loads for step 0
    int pg = gw * STEPS * 32 + grp * 8;
    int4 la = *reinterpret_cast<const int4*>(&lab[lb + pg]);
    int4 lc = *reinterpret_cast<const int4*>(&lab[lb + pg + 4]);
    f32x4 v0 = *reinterpret_cast<const f32x4*>(&xr0[pg]);
    f32x4 v1 = *reinterpret_cast<const f32x4*>(&xr0[pg + 4]);
    f32x4 v2 = *reinterpret_cast<const f32x4*>(&xr1[pg]);
    f32x4 v3 = *reinterpret_cast<const f32x4*>(&xr1[pg + 4]);

#pragma unroll
    for (int s = 0; s < STEPS; ++s) {
        const int pgn = pg + 32;
        int4 lan{}, lcn{};
        f32x4 w0{}, w1{}, w2{}, w3{};
        if (s + 1 < STEPS) {                         // issue NEXT step's loads first
            lan = *reinterpret_cast<const int4*>(&lab[lb + pgn]);
            lcn = *reinterpret_cast<const int4*>(&lab[lb + pgn + 4]);
            w0 = *reinterpret_cast<const f32x4*>(&xr0[pgn]);
            w1 = *reinterpret_cast<const f32x4*>(&xr0[pgn + 4]);
            w2 = *reinterpret_cast<const f32x4*>(&xr1[pgn]);
            w3 = *reinterpret_cast<const f32x4*>(&xr1[pgn + 4]);
        }

        bf16x8 a0, a1, b0, b1;
        a0[0]=f2bf(v0.x); a0[1]=f2bf(v0.y); a0[2]=f2bf(v0.z); a0[3]=f2bf(v0.w);
        a0[4]=f2bf(v1.x); a0[5]=f2bf(v1.y); a0[6]=f2bf(v1.z); a0[7]=f2bf(v1.w);
        a1[0]=f2bf(v2.x); a1[1]=f2bf(v2.y); a1[2]=f2bf(v2.z); a1[3]=f2bf(v2.w);
        a1[4]=f2bf(v3.x); a1[5]=f2bf(v3.y); a1[6]=f2bf(v3.z); a1[7]=f2bf(v3.w);
        const int lj[8] = {la.x, la.y, la.z, la.w, lc.x, lc.y, lc.z, lc.w};
#pragma unroll
        for (int j = 0; j < 8; ++j) {
            b0[j] = (lj[j] == row)      ? (short)0x3F80 : (short)0;
            b1[j] = (lj[j] == row + 16) ? (short)0x3F80 : (short)0;
        }

        // stash bf16(x) for pass 2
        *reinterpret_cast<bf16x8*>(&sr0[pg]) = a0;
        *reinterpret_cast<bf16x8*>(&sr1[pg]) = a1;

        acc00 = __builtin_amdgcn_mfma_f32_16x16x32_bf16(a0, b0, acc00, 0, 0, 0);
        acc10 = __builtin_amdgcn_mfma_f32_16x16x32_bf16(a1, b0, acc10, 0, 0, 0);
        acc01 = __builtin_amdgcn_mfma_f32_16x16x32_bf16(a0, b1, acc01, 0, 0, 0);
        acc11 = __builtin_amdgcn_mfma_f32_16x16x32_bf16(a1, b1, acc11, 0, 0, 0);
        accC0 = __builtin_amdgcn_mfma_f32_16x16x32_bf16(ones, b0, accC0, 0, 0, 0);
        accC1 = __builtin_amdgcn_mfma_f32_16x16x32_bf16(ones, b1, accC1, 0, 0, 0);

        la = lan; lc = lcn; v0 = w0; v1 = w1; v2 = w2; v3 = w3; pg = pgn;
    }

    __shared__ float s_red[4][FDIM * KLAB];
#pragma unroll
    for (int i = 0; i < 4; ++i) {
        // C layout: col = lane&15, row = (lane>>4)*4 + i  [measured m89]
        const int fr = grp * 4 + i;
        s_red[w][(fr)      * KLAB + row]      = acc00[i];
        s_red[w][(fr)      * KLAB + row + 16] = acc01[i];
        s_red[w][(fr + 16) * KLAB + row]      = acc10[i];
        s_red[w][(fr + 16) * KLAB + row + 16] = acc11[i];
    }
    __syncthreads();
    float* gs = g_sums + (size_t)b * FDIM * KLAB;
    for (int i = tid; i < FDIM * KLAB; i += 256)
        atomicAdd(&gs[i], s_red[0][i] + s_red[1][i] + s_red[2][i] + s_red[3][i]);
    if (l < 16) {   // counts: row 0 of ones-GEMM
        atomicAdd(&g_cnt[b * KLAB + l],      accC0[0]);
        atomicAdd(&g_cnt[b * KLAB + l + 16], accC1[0]);
    }
}

// Pass 2: per-pixel ||mu_label - x|| from the bf16 stash, hinge^2, per-(b,k) sums.
__global__ __launch_bounds__(256) void k_var(
    const short* __restrict__ xbf, const int* __restrict__ lab,
    const float* __restrict__ g_sums, const float* __restrict__ g_cnt,
    float* __restrict__ g_vsum)
{
    __shared__ float mu_s[FDIM][KLAB];
    __shared__ float vloc[KLAB];
    const int tid = threadIdx.x;
    const int b = blockIdx.y;
    for (int i = tid; i < FDIM * KLAB; i += 256) {
        const int k = i & (KLAB - 1);
        (&mu_s[0][0])[i] = g_sums[(size_t)b * FDIM * KLAB + i] / fmaxf(g_cnt[b * KLAB + k], 1.f);
    }
    if (tid < KLAB) vloc[tid] = 0.f;
    __syncthreads();

    const int n0 = blockIdx.x * 2048 + tid * 8;      // 8 px/thread, grid(128,B)
    const size_t lb = (size_t)b * NPIX;
    const int4 l4a = *reinterpret_cast<const int4*>(&lab[lb + n0]);
    const int4 l4b = *reinterpret_cast<const int4*>(&lab[lb + n0 + 4]);
    const int k0 = l4a.x & 31, k1 = l4a.y & 31, k2 = l4a.z & 31, k3 = l4a.w & 31;
    const int k4 = l4b.x & 31, k5 = l4b.y & 31, k6 = l4b.z & 31, k7 = l4b.w & 31;
    const short* xp = xbf + (size_t)b * FDIM * NPIX + n0;

    bf16x8 A = *reinterpret_cast<const bf16x8*>(xp);
    bf16x8 B = *reinterpret_cast<const bf16x8*>(xp + NPIX);
    float d0=0.f,d1=0.f,d2=0.f,d3=0.f,d4=0.f,d5=0.f,d6=0.f,d7=0.f;
#pragma unroll
    for (int f = 0; f < FDIM; ++f) {
        bf16x8 Cn{};
        if (f + 2 < FDIM) Cn = *reinterpret_cast<const bf16x8*>(xp + (size_t)(f + 2) * NPIX);
        const float* mf = &mu_s[f][0];
        float t;
        t = bf2f(A[0]) - mf[k0]; d0 += t * t;
        t = bf2f(A[1]) - mf[k1]; d1 += t * t;
        t = bf2f(A[2]) - mf[k2]; d2 += t * t;
        t = bf2f(A[3]) - mf[k3]; d3 += t * t;
        t = bf2f(A[4]) - mf[k4]; d4 += t * t;
        t = bf2f(A[5]) - mf[k5]; d5 += t * t;
        t = bf2f(A[6]) - mf[k6]; d6 += t * t;
        t = bf2f(A[7]) - mf[k7]; d7 += t * t;
        A = B; B = Cn;
    }
    float h;
    h = fmaxf(sqrtf(d0 + EPSF) - 0.5f, 0.f); atomicAdd(&vloc[k0], h * h);
    h = fmaxf(sqrtf(d1 + EPSF) - 0.5f, 0.f); atomicAdd(&vloc[k1], h * h);
    h = fmaxf(sqrtf(d2 + EPSF) - 0.5f, 0.f); atomicAdd(&vloc[k2], h * h);
    h = fmaxf(sqrtf(d3 + EPSF) - 0.5f, 0.f); atomicAdd(&vloc[k3], h * h);
    h = fmaxf(sqrtf(d4 + EPSF) - 0.5f, 0.f); atomicAdd(&vloc[k4], h * h);
    h = fmaxf(sqrtf(d5 + EPSF) - 0.5f, 0.f); atomicAdd(&vloc[k5], h * h);
    h = fmaxf(sqrtf(d6 + EPSF) - 0.5f, 0.f); atomicAdd(&vloc[k6], h * h);
    h = fmaxf(sqrtf(d7 + EPSF) - 0.5f, 0.f); atomicAdd(&vloc[k7], h * h);
    __syncthreads();
    if (tid < KLAB) atomicAdd(&g_vsum[b * KLAB + tid], vloc[tid]);
}

// Epilogue: all-batch mu staged once in LDS; wave-shuffle reductions; scalar out.
__global__ __launch_bounds__(256) void k_final(
    const float* __restrict__ g_sums, const float* __restrict__ g_cnt,
    const float* __restrict__ g_vsum, float* __restrict__ out)
{
    __shared__ float mu8[BATCH][FDIM][KLAB];   // 32 KB
    __shared__ float cnt8[BATCH][KLAB];
    __shared__ float tot[BATCH];
    const int tid = threadIdx.x;
    const int l = tid & 63, w = tid >> 6;

    for (int i = tid; i < BATCH * FDIM * KLAB; i += 256) {
        const int bb = i >> 10, k = i & 31;
        (&mu8[0][0][0])[i] = g_sums[i] / fmaxf(g_cnt[bb * KLAB + k], 1.f);
    }
    (&cnt8[0][0])[tid] = g_cnt[tid];           // 256 == BATCH*KLAB
    __syncthreads();

    for (int half = 0; half < 2; ++half) {
        const int bb = w + half * 4;           // wave w handles batches w, w+4
        float pres = 0.f, varp = 0.f, regp = 0.f, distp = 0.f;
        if (l < KLAB && cnt8[bb][l] > 0.f) {
            pres = 1.f;
            varp = g_vsum[bb * KLAB + l] / fmaxf(cnt8[bb][l], 1.f);
            float s = 0.f;
            for (int f = 0; f < FDIM; ++f) { float m = mu8[bb][f][l]; s += m * m; }
            regp = sqrtf(s + EPSF);
        }
        for (int p = l; p < KLAB * KLAB; p += 64) {
            const int i = p >> 5, j = p & 31;
            if (i < j && cnt8[bb][i] > 0.f && cnt8[bb][j] > 0.f) {
                float s = 0.f;
                for (int f = 0; f < FDIM; ++f) {
                    float d = mu8[bb][f][i] - mu8[bb][f][j]; s += d * d;
                }
                const float dist = sqrtf(s + EPSF);
                const float hg = fmaxf(1.5f - dist, 0.f);
                distp += hg * hg;
            }
        }
        for (int m = 32; m > 0; m >>= 1) {     // 64-lane butterfly
            pres  += __shfl_xor(pres,  m, 64);
            varp  += __shfl_xor(varp,  m, 64);
            regp  += __shfl_xor(regp,  m, 64);
            distp += __shfl_xor(distp, m, 64);
        }
        if (l == 0) {
            const float C = pres;
            const float var_b = (C > 0.f) ? varp / fmaxf(C, 1.f) : 0.f;
            const float dis_b = (C > 2.f) ? distp / fmaxf(C * (C - 1.f), 1.f) : 0.f;
            const float reg_b = (C > 1.f) ? regp : 0.f;
            tot[bb] = var_b + dis_b + 0.001f * reg_b;
        }
    }
    __syncthreads();
    if (tid == 0) {
        float t = 0.f;
        for (int bb = 0; bb < BATCH; ++bb) t += tot[bb];
        out[0] = t;
    }
}

extern "C" void kernel_launch(void* const* d_in, const int* in_sizes, int n_in,
                              void* d_out, int out_size, void* d_ws, size_t ws_size,
                              hipStream_t stream) {
    const float* x = (const float*)d_in[0];
    const int* lab = (const int*)d_in[1];
    float* out = (float*)d_out;

    // ws: xbf [B][F][N] bf16 (128 MiB) | sums [B][F][K] | counts [B][K] | vsums [B][K]
    const size_t XBF_BYTES = (size_t)BATCH * FDIM * NPIX * 2;
    short* xbf    = (short*)d_ws;
    float* g_sums = (float*)((char*)d_ws + XBF_BYTES);
    float* g_cnt  = g_sums + (size_t)BATCH * FDIM * KLAB;
    float* g_vsum = g_cnt + (size_t)BATCH * KLAB;
    hipMemsetAsync(g_sums, 0, (size_t)(BATCH * FDIM * KLAB + 2 * BATCH * KLAB) * 4, stream);

    dim3 grid1(256, BATCH);    // 1024 waves/batch, 8 pipelined MFMA steps each
    k_msums<<<grid1, 256, 0, stream>>>(x, lab, g_sums, g_cnt, xbf);
    dim3 grid2(128, BATCH);    // 2048 px/block, 8 px/thread
    k_var<<<grid2, 256, 0, stream>>>(xbf, lab, g_sums, g_cnt, g_vsum);
    k_final<<<1, 256, 0, stream>>>(g_sums, g_cnt, g_vsum, out);
}